// Round 3
// baseline (116.588 us; speedup 1.0000x reference)
//
#include <hip/hip_runtime.h>

// Gaussian 3x3 conv forward, B=64, C=1, H=W=512, N_MULT=1.
// taps = max(rint(clamp(w,0.001,0.999)*clamp(wf,1.001,254.999)), 0.001), then
// 3x3 conv, zero padding=1. Output [1,64,1,512,512] fp32 (flat layout == input).
//
// v4 == v1 (empirical best: 110.5us prior session, 111.3us R0). Session A/B
// results: RR=16 (v2) cost +6us (occupancy 32->16 waves/CU); rolling stores +
// XCD swizzle + merged edge load (v3) were neutral-to-negative (+1us beyond
// fill noise). Conv dispatch is ~27us vs a ~25us mixed-stream HBM floor
// (151 MB at the ~6.2 TB/s the harness fills themselves achieve) -- within
// ~8% of roofline; the 111us metric is dominated by ~86us of harness fills.
//
// Row-blocked 8x: each thread computes an 8-row x 4-col (float4) output tile.
// Horizontal halos come from cross-lane shuffles (c.w of lane-1 / c.x of lane+1);
// only wave-edge lanes (0 / 63) issue a 1-active-lane scalar load. Output uses
// non-temporal stores (no reuse; keep L2/L3 for the input rows).

#define BB 64
#define HH 512
#define WW 512
#define W4 (WW / 4)   // 128 float4 per row
#define RR 8          // output rows per thread

typedef float vfloat4 __attribute__((ext_vector_type(4)));  // clang vector: OK for nontemporal builtin

__global__ __launch_bounds__(256) void gauss3x3_kernel(
    const float* __restrict__ in,     // [B,1,H,W]
    const float* __restrict__ wgt,    // [1,9]
    const float* __restrict__ wfac,   // [1,1]
    float* __restrict__ out)          // [1,B,1,H,W]
{
    // Derive the 9 taps (redundant per thread; scalar broadcast loads).
    float wf = fminf(fmaxf(wfac[0], 1.001f), 254.999f);
    float k[9];
#pragma unroll
    for (int i = 0; i < 9; ++i) {
        float wc = fminf(fmaxf(wgt[i], 0.001f), 0.999f);
        k[i] = fmaxf(rintf(wc * wf), 0.001f);   // rintf = round-half-even = jnp.round
    }

    const int tid   = blockIdx.x * blockDim.x + threadIdx.x; // [0, B*(H/RR)*W4)
    const int lane  = threadIdx.x & 63;
    const int x4    = tid & (W4 - 1);              // lane-varying: column (float4)
    const int strip = (tid >> 7) & (HH / RR - 1);  // wave-uniform: 8-row strip
    const int b     = tid >> 13;                   // wave-uniform: batch
    if (b >= BB) return;

    const int y0 = strip * RR;
    const int x0 = x4 * 4;
    const float* img  = in  + (size_t)b * HH * WW;
    float*       outp = out + (size_t)b * HH * WW;

    float4 acc[RR];
#pragma unroll
    for (int i = 0; i < RR; ++i) acc[i] = make_float4(0.f, 0.f, 0.f, 0.f);

    // Input rows j=0..RR+1 map to ry = y0-1+j. Input row j contributes to:
    //   out i=j   with tap row 0 (k[0..2], dy=-1)
    //   out i=j-1 with tap row 1 (k[3..5], dy= 0)
    //   out i=j-2 with tap row 2 (k[6..8], dy=+1)
#pragma unroll
    for (int j = 0; j < RR + 2; ++j) {
        const int ry = y0 - 1 + j;
        float4 c = make_float4(0.f, 0.f, 0.f, 0.f);
        float  l = 0.f, r = 0.f;
        if (ry >= 0 && ry < HH) {                  // wave-uniform branch
            const float* row = img + (size_t)ry * WW;
            c = *(const float4*)(row + x0);        // aligned 16B load
            l = __shfl_up(c.w, 1);                 // lane-1's last element
            r = __shfl_down(c.x, 1);               // lane+1's first element
            if (lane == 0)                         // wave-edge fix-up (1 active lane)
                l = (x0 > 0) ? row[x0 - 1] : 0.f;
            if (lane == 63)
                r = (x0 + 4 < WW) ? row[x0 + 4] : 0.f;
        }
#pragma unroll
        for (int t = 0; t < 3; ++t) {
            const int i = j - t;
            if (i >= 0 && i < RR) {
                const float kl = k[t * 3 + 0];
                const float kc = k[t * 3 + 1];
                const float kr = k[t * 3 + 2];
                acc[i].x = fmaf(kl, l,   fmaf(kc, c.x, fmaf(kr, c.y, acc[i].x)));
                acc[i].y = fmaf(kl, c.x, fmaf(kc, c.y, fmaf(kr, c.z, acc[i].y)));
                acc[i].z = fmaf(kl, c.y, fmaf(kc, c.z, fmaf(kr, c.w, acc[i].z)));
                acc[i].w = fmaf(kl, c.z, fmaf(kc, c.w, fmaf(kr, r,   acc[i].w)));
            }
        }
    }

#pragma unroll
    for (int i = 0; i < RR; ++i) {
        vfloat4* dst = (vfloat4*)(outp + (size_t)(y0 + i) * WW + x0);
        vfloat4 v = { acc[i].x, acc[i].y, acc[i].z, acc[i].w };
        __builtin_nontemporal_store(v, dst);       // streamed; output has no reuse
    }
}

extern "C" void kernel_launch(void* const* d_in, const int* in_sizes, int n_in,
                              void* d_out, int out_size, void* d_ws, size_t ws_size,
                              hipStream_t stream) {
    const float* in   = (const float*)d_in[0];   // [64,1,512,512]
    const float* wgt  = (const float*)d_in[1];   // [1,9]
    const float* wfac = (const float*)d_in[2];   // [1,1]
    float* out = (float*)d_out;                  // [1,64,1,512,512]

    const int total = BB * (HH / RR) * W4;       // 524,288 threads
    const int block = 256;
    const int grid  = total / block;             // 2048
    gauss3x3_kernel<<<grid, block, 0, stream>>>(in, wgt, wfac, out);
}